// Round 8
// baseline (127.114 us; speedup 1.0000x reference)
//
#include <hip/hip_runtime.h>
#include <hip/hip_bf16.h>

#define Bn 4096
#define Ln 512
#define Hn 32
#define MT 4  // m-tiles per block (grid = 128 bn x 8 mg)

using bf16x8 = __attribute__((ext_vector_type(8))) __bf16;
using f32x4  = __attribute__((ext_vector_type(4))) float;

#define GLOAD_LDS16(g, l)                                                          \
  __builtin_amdgcn_global_load_lds(                                                \
      (const __attribute__((address_space(1))) void*)(g),                          \
      (__attribute__((address_space(3))) void*)(l), 16, 0, 0)

__device__ __forceinline__ unsigned short f2bf(float x) {
  unsigned int u = __float_as_uint(x);
  unsigned int r = (u + 0x7FFFu + ((u >> 16) & 1u)) >> 16;
  return (unsigned short)r;
}

// Convert W1 [512*32*512] f32 -> bf16. Masked (upper-triangular) groups are
// ZERO-FILLED without reading W1 (d_ws content at first call is undefined;
// relying on poison being benign was a latent flake). Reads ~half, writes all.
__global__ __launch_bounds__(256) void prep_w1_kernel(const float* __restrict__ W1,
                                                      unsigned short* __restrict__ W1b) {
  int idx = blockIdx.x * 256 + threadIdx.x;   // float4 group index
  const int n  = idx >> 7;                    // row in [0, 16384)
  const int c0 = (idx & 127) * 4;             // first col of group
  const int i  = n >> 5;                      // latent step of this row
  ushort4 o;
  if (c0 > i) {
    o.x = 0; o.y = 0; o.z = 0; o.w = 0;       // fully-masked group
  } else {
    const float4 f = reinterpret_cast<const float4*>(W1)[idx];
    o.x = f2bf(f.x); o.y = f2bf(f.y); o.z = f2bf(f.z); o.w = f2bf(f.w);
  }
  reinterpret_cast<ushort4*>(W1b)[idx] = o;
}

// Build V [4096,512] bf16
__global__ __launch_bounds__(256) void prep_v_kernel(const float* __restrict__ mu,
                                                     const float* __restrict__ log_var,
                                                     const float* __restrict__ eps0,
                                                     unsigned short* __restrict__ Vb) {
  int idx = blockIdx.x * 256 + threadIdx.x;
  int b = idx >> 9, j = idx & 511;
  float v;
  if (j == 0) {
    v = eps0[b] * expf(0.5f * log_var[(size_t)b * Ln]) + mu[(size_t)b * Ln];
  } else {
    v = mu[(size_t)b * Ln + j - 1];
  }
  Vb[idx] = f2bf(v);
}

// Fused: Hm = leaky_relu(V @ W1^T + b1); out = Hm @ W2^T + b2; sample.
// Hybrid operand路径: W1 (B) staged through double-buffered swizzled LDS
// (shared by 2 waves); V (A) loaded DIRECT global->register per wave
// (wave pairs read identical bytes -> L1 serves the second). LDS traffic
// per block-iter halves vs both-staged; LDS 32 KiB -> 3 blocks/CU.
// Counted-vmcnt pipeline across the flattened (m-tile, k) loop.
// bn grouped by 4 per XCD so each 64B output line is written within one XCD.
__global__ __launch_bounds__(256, 3) void gemm_fused_kernel(
    const unsigned short* __restrict__ Vb,   // [4096,512] bf16
    const unsigned short* __restrict__ W1b,  // [16384,512] bf16
    const float* __restrict__ b1,            // [512,32]
    const float* __restrict__ W2,            // [512,2,32]
    const float* __restrict__ b2,            // [512,2]
    const float* __restrict__ eps,           // [4096,512]
    float* __restrict__ out)                 // [3, 4096, 512]
{
  const int tid  = threadIdx.x;
  const int wid  = tid >> 6;
  const int lane = tid & 63;
  const int l15  = lane & 15;
  const int lq   = lane >> 4;

  // ---- group-of-4 XCD striping: group g = bn>>2 lives on XCD g&7.
  // Heavy groups first; bn within group changes every 8 blocks (write-merge),
  // mg fastest. ksteps balanced across XCDs.
  const int bid  = blockIdx.x;
  const int xcd  = bid & 7;
  const int s    = bid >> 3;              // 0..127
  const int g    = xcd + 8 * (3 - (s >> 5));
  const int bn   = g * 4 + ((s >> 3) & 3);
  const int mg   = s & 7;
  const int mb   = mg * (MT * 128);
  const int nb   = bn * 128;

  // triangular cutoff: block's i in [bn*4, bn*4+3] -> j <= bn*4+3
  const int ksteps = min(8, (bn + 16) >> 4);  // ceil((4bn+4)/64)

  __shared__ unsigned short Bs[2 * 128 * 64];  // 2 x 16 KiB (W1 only)

  // ---- B staging: chunk = 8 rows x 128 B = 1 KiB; lane -> (row=lane>>3, slot=lane&7).
  // LDS linear slot (row, s) receives global element (row, s ^ row) [16B slots]
  // => pre-swizzled SOURCE address.
  const int rowc = lane >> 3;
  const int sswz = (lane & 7) ^ rowc;
  const unsigned short* gB = W1b + (size_t)(nb + wid * 32 + rowc) * Ln + sswz * 8;
  unsigned short* lB = Bs + wid * 2048;

  auto STAGE_B = [&](int buf, int k0e) {
#pragma unroll
    for (int j = 0; j < 4; ++j)
      GLOAD_LDS16(gB + k0e + (size_t)j * 8 * Ln, lB + buf * 8192 + j * 512);
  };

  // ---- A direct-from-global: wave's m-rows = mb + mt*128 + (wid>>1)*64 + l15 + f*16
  const unsigned short* gA = Vb + (size_t)(mb + (wid >> 1) * 64 + l15) * Ln;

  // ---- B fragment reads: row = brow + f*16; global k-slot s_g = ks2*4+lq;
  // linear slot = s_g ^ (row&7); row&7 == l15&7.
  const int brow = (wid & 1) * 64 + l15;
  const int swz7 = l15 & 7;

  f32x4 acc[4][4];  // acc[fn][fm]: rows = n-side (i,h), cols = batch
#pragma unroll
  for (int fn = 0; fn < 4; ++fn)
#pragma unroll
    for (int fm = 0; fm < 4; ++fm) acc[fn][fm] = f32x4{0.f, 0.f, 0.f, 0.f};

  float* mus = out;
  float* lvs = out + (size_t)Bn * Ln;
  float* smp = out + (size_t)2 * Bn * Ln;

  int buf = 0;
  STAGE_B(0, 0);

  for (int mt = 0; mt < MT; ++mt) {
    for (int k = 0; k < ksteps; ++k) {
      int kn = k + 1, mtn = mt;
      if (kn == ksteps) { kn = 0; ++mtn; }
      const bool more = (mtn < MT);
      if (more) STAGE_B(buf ^ 1, kn * 64);  // 4 newest VMEM ops (next B-tile)

      // A fragments for the CURRENT iter: 8 x dwordx4 (compiler-waited)
      bf16x8 a[2][4];
      {
        const unsigned short* pa = gA + (size_t)mt * (128 * Ln) + k * 64;
#pragma unroll
        for (int ks2 = 0; ks2 < 2; ++ks2)
#pragma unroll
          for (int f = 0; f < 4; ++f)
            a[ks2][f] = *reinterpret_cast<const bf16x8*>(
                pa + (size_t)f * 16 * Ln + (ks2 * 4 + lq) * 8);
      }

      if (more) {
        // outstanding newest: 4 stage + 8 A = 12; B(current) is older -> done
        asm volatile("s_waitcnt vmcnt(12)" ::: "memory");
      } else {
        // no prefetch issued: 8 A outstanding; drain everything older (last B)
        asm volatile("s_waitcnt vmcnt(8)" ::: "memory");
      }
      __builtin_amdgcn_s_barrier();
      __builtin_amdgcn_sched_barrier(0);  // pin ds_reads below the barrier

      const int cofs = buf * 8192;
#pragma unroll
      for (int ks2 = 0; ks2 < 2; ++ks2) {
        const int se = ((ks2 * 4 + lq) ^ swz7) * 8;
        bf16x8 b[4];
#pragma unroll
        for (int f = 0; f < 4; ++f)
          b[f] = *reinterpret_cast<const bf16x8*>(Bs + cofs + (brow + f * 16) * 64 + se);
#pragma unroll
        for (int fn = 0; fn < 4; ++fn)
#pragma unroll
          for (int fm = 0; fm < 4; ++fm)
            acc[fn][fm] = __builtin_amdgcn_mfma_f32_16x16x32_bf16(b[fn], a[ks2][fm],
                                                                  acc[fn][fm], 0, 0, 0);
      }

      if (k == ksteps - 1) {
        // ======== per-m-tile epilogue (block-uniform branch) ========
        // Scratch: just-consumed B buffer (prefetch writes buf^1; disjoint).
        // Layout: S[2][4][128] f32 = 4 KiB ({mu,lv} x i_local x row).
        float* S = reinterpret_cast<float*>(Bs + buf * 8192);
        __builtin_amdgcn_s_barrier();  // all waves done reading Bs[buf]

        const int wrow = (wid >> 1) * 64;
#pragma unroll
        for (int il = 0; il < 2; ++il) {
          const int i   = bn * 4 + (wid & 1) * 2 + il;
          const int icl = (wid & 1) * 2 + il;
          float4 b1q[2], w20q[2], w21q[2];
#pragma unroll
          for (int q = 0; q < 2; ++q) {
            const int hb = q * 16 + lq * 4;
            b1q[q]  = *reinterpret_cast<const float4*>(b1 + i * Hn + hb);
            w20q[q] = *reinterpret_cast<const float4*>(W2 + (i * 2 + 0) * Hn + hb);
            w21q[q] = *reinterpret_cast<const float4*>(W2 + (i * 2 + 1) * Hn + hb);
          }
          const float bias0 = b2[i * 2 + 0];
          const float bias1 = b2[i * 2 + 1];
#pragma unroll
          for (int fm = 0; fm < 4; ++fm) {
            float p0 = 0.f, p1 = 0.f;
#pragma unroll
            for (int q = 0; q < 2; ++q) {
              const f32x4& A = acc[il * 2 + q][fm];
              const float* b1f = reinterpret_cast<const float*>(&b1q[q]);
              const float* w0f = reinterpret_cast<const float*>(&w20q[q]);
              const float* w1f = reinterpret_cast<const float*>(&w21q[q]);
#pragma unroll
              for (int r = 0; r < 4; ++r) {
                float x  = A[r] + b1f[r];
                float hv = fmaxf(x, 0.01f * x);  // leaky_relu (slope 0.01)
                p0 += hv * w0f[r];
                p1 += hv * w1f[r];
              }
            }
            p0 += __shfl_xor(p0, 16);
            p0 += __shfl_xor(p0, 32);
            p1 += __shfl_xor(p1, 16);
            p1 += __shfl_xor(p1, 32);
            if (lq == 0) {
              const int r = wrow + fm * 16 + l15;
              S[icl * 128 + r]       = p0 + bias0;
              S[512 + icl * 128 + r] = p1 + bias1;
            }
          }
        }
        asm volatile("s_waitcnt lgkmcnt(0)" ::: "memory");  // ds_writes visible
        __builtin_amdgcn_s_barrier();

        if (tid < 128) {  // wave-uniform: waves 0,1 active
          const int    r = tid;
          const size_t o = (size_t)(mb + mt * 128 + r) * Ln + bn * 4;
          float4 muv, lvv;
          muv.x = S[r];       muv.y = S[128 + r]; muv.z = S[256 + r]; muv.w = S[384 + r];
          lvv.x = S[512 + r]; lvv.y = S[640 + r]; lvv.z = S[768 + r]; lvv.w = S[896 + r];
          const float4 ep = *reinterpret_cast<const float4*>(eps + o);
          float4 sm;
          sm.x = ep.x * __builtin_exp2f(lvv.x * 0.7213475204444817f) + muv.x;
          sm.y = ep.y * __builtin_exp2f(lvv.y * 0.7213475204444817f) + muv.y;
          sm.z = ep.z * __builtin_exp2f(lvv.z * 0.7213475204444817f) + muv.z;
          sm.w = ep.w * __builtin_exp2f(lvv.w * 0.7213475204444817f) + muv.w;
          *reinterpret_cast<float4*>(mus + o) = muv;
          *reinterpret_cast<float4*>(lvs + o) = lvv;
          *reinterpret_cast<float4*>(smp + o) = sm;
        }
        // reset accumulators for the next m-tile
#pragma unroll
        for (int fn = 0; fn < 4; ++fn)
#pragma unroll
          for (int fm = 0; fm < 4; ++fm) acc[fn][fm] = f32x4{0.f, 0.f, 0.f, 0.f};
      }
      __builtin_amdgcn_s_barrier();  // buffer free for next STAGE_B
      buf ^= 1;
    }
  }
}

extern "C" void kernel_launch(void* const* d_in, const int* in_sizes, int n_in,
                              void* d_out, int out_size, void* d_ws, size_t ws_size,
                              hipStream_t stream) {
  const float* mu      = (const float*)d_in[0];
  const float* log_var = (const float*)d_in[1];
  const float* eps0    = (const float*)d_in[2];
  const float* eps     = (const float*)d_in[3];
  const float* W1      = (const float*)d_in[4];
  const float* b1      = (const float*)d_in[5];
  const float* W2      = (const float*)d_in[6];
  const float* b2      = (const float*)d_in[7];
  float* out = (float*)d_out;

  unsigned short* Vb  = (unsigned short*)d_ws;                                  // 4 MiB
  unsigned short* W1b = (unsigned short*)((char*)d_ws + (size_t)Bn * Ln * 2);   // 16 MiB

  prep_v_kernel<<<(Bn * Ln) / 256, 256, 0, stream>>>(mu, log_var, eps0, Vb);
  prep_w1_kernel<<<(Ln * Hn * Ln) / 4 / 256, 256, 0, stream>>>(W1, W1b);
  gemm_fused_kernel<<<128 * (32 / MT), 256, 0, stream>>>(
      Vb, W1b, b1, W2, b2, eps, out);
}